// Round 4
// baseline (50.171 us; speedup 1.0000x reference)
//
#include <hip/hip_runtime.h>

// REINFORCE fused kernel, chunked with truncated-horizon halo.
// B=1024 rows, T=8192. Each row split into 4 chunks of 2048; each block (256 thr)
// owns one chunk; incoming carry from a 1024-elem halo (gamma^1024=3.35e-5).
// Round-4: fix nontemporal-store type (ext_vector_type float4, not HIP_vector_type).
// XCD swizzle (row's 4 chunks share an XCD -> halo = L2 hit),
// non-temporal output stores (keep inputs L3-resident across replays),
// single barrier.

#define T_LEN 8192
#define CHUNK 2048
#define NT 256
#define CSEG 8
#define GAMMA_F 0.99f
#define CLIP_F 5.0f
#define EPS_F 1e-7f

typedef float f32x4 __attribute__((ext_vector_type(4)));

constexpr double dgpow(int n) {
    double r = 1.0;
    for (int i = 0; i < n; ++i) r *= 0.99;
    return r;
}

__device__ __forceinline__ float r2f(float w, float x) {
    float s = 1.0f / (1.0f + __expf(-x));
    return w * w * __logf(s + EPS_F);
}

__global__ __launch_bounds__(NT)
void reinforce_kernel(const float* __restrict__ log_probs,
                      const float* __restrict__ logits,
                      const float* __restrict__ weight,
                      float* __restrict__ out,   // [2*B*T]: objective, then cumulative
                      long BT) {
    // XCD-aware decode: all 4 chunks of a row share bid%8 -> same XCD L2.
    const int bid  = blockIdx.x;          // 0..4095
    const int k    = bid & 7;             // xcd slot
    const int j    = bid >> 3;            // 0..511
    const int chunk = j & 3;              // 0..3
    const int row   = (j >> 2) * 8 + k;   // 0..1023

    const long rbase = (long)row * T_LEN;
    const long cbase = rbase + (long)chunk * CHUNK;
    const int tid  = threadIdx.x;
    const int lane = tid & 63;
    const int wave = tid >> 6;
    const int seg  = tid * CSEG;

    __shared__ float RED[4];
    __shared__ float WT[4];

    // ---- issue ALL global loads up front ----
    f32x4 hw, hx;
    if (chunk != 3) {
        const long hbase = cbase + CHUNK + (long)tid * 4;
        hw = *reinterpret_cast<const f32x4*>(weight + hbase);
        hx = *reinterpret_cast<const f32x4*>(logits + hbase);
    }
    const f32x4* w4  = reinterpret_cast<const f32x4*>(weight + cbase + seg);
    const f32x4* x4  = reinterpret_cast<const f32x4*>(logits + cbase + seg);
    const f32x4* lp4 = reinterpret_cast<const f32x4*>(log_probs + cbase + seg);
    f32x4 wq0 = w4[0], wq1 = w4[1];
    f32x4 xq0 = x4[0], xq1 = x4[1];
    f32x4 lq0 = lp4[0], lq1 = lp4[1];

    // ---- chunk r2 ----
    float r2[CSEG], wv[CSEG];
#pragma unroll
    for (int e = 0; e < 4; ++e) { wv[e] = wq0[e]; wv[4 + e] = wq1[e]; }
#pragma unroll
    for (int e = 0; e < 4; ++e) { r2[e] = r2f(wq0[e], xq0[e]); r2[4 + e] = r2f(wq1[e], xq1[e]); }

    // ---- per-thread suffix sum (zero carry) ----
    float S = 0.0f;
#pragma unroll
    for (int jj = CSEG - 1; jj >= 0; --jj) S = r2[jj] + GAMMA_F * S;

    // ---- wave suffix scan (decay gamma^8 per lane step) ----
    float X = S;
    {
        constexpr float G8   = (float)dgpow(8);
        constexpr float G16  = (float)dgpow(16);
        constexpr float G32  = (float)dgpow(32);
        constexpr float G64  = (float)dgpow(64);
        constexpr float G128 = (float)dgpow(128);
        constexpr float G256 = (float)dgpow(256);
        float t;
        t = __shfl_down(X, 1, 64);  if (lane + 1  < 64) X += G8   * t;
        t = __shfl_down(X, 2, 64);  if (lane + 2  < 64) X += G16  * t;
        t = __shfl_down(X, 4, 64);  if (lane + 4  < 64) X += G32  * t;
        t = __shfl_down(X, 8, 64);  if (lane + 8  < 64) X += G64  * t;
        t = __shfl_down(X, 16, 64); if (lane + 16 < 64) X += G128 * t;
        t = __shfl_down(X, 32, 64); if (lane + 32 < 64) X += G256 * t;
    }
    float Ex = __shfl_down(X, 1, 64);
    if (lane == 63) Ex = 0.0f;

    // ---- halo partial (independent of scan) ----
    if (chunk != 3) {
        float h0 = r2f(hw[0], hx[0]), h1 = r2f(hw[1], hx[1]);
        float h2 = r2f(hw[2], hx[2]), h3 = r2f(hw[3], hx[3]);
        float hS = h0 + GAMMA_F * (h1 + GAMMA_F * (h2 + GAMMA_F * h3));
        const float L2G4 = 4.0f * -0.014499569695f;   // 4*log2(0.99)
        float part = exp2f((float)tid * L2G4) * hS;
#pragma unroll
        for (int off = 1; off < 64; off <<= 1)
            part += __shfl_xor(part, off, 64);
        if (lane == 0) RED[wave] = part;
    }
    if (lane == 0) WT[wave] = X;

    __syncthreads();   // single barrier

    float c_in = (chunk != 3) ? (RED[0] + RED[1] + RED[2] + RED[3]) : 0.0f;

    constexpr float G512  = (float)dgpow(512);
    constexpr float G1024 = (float)dgpow(1024);
    constexpr float G1536 = (float)dgpow(1536);
    float WC;
    if (wave == 3)      WC = c_in;
    else if (wave == 2) WC = WT[3] + G512 * c_in;
    else if (wave == 1) WC = WT[2] + G512 * WT[3] + G1024 * c_in;
    else                WC = WT[1] + G512 * WT[2] + G1024 * WT[3] + G1536 * c_in;

    const float L2G8 = 8.0f * -0.014499569695f;   // 8*log2(0.99)
    float K = Ex + exp2f((float)(63 - lane) * L2G8) * WC;

    // ---- fixup scan + fused epilogue + non-temporal stores ----
    f32x4* go4 = reinterpret_cast<f32x4*>(out + cbase + seg);
    f32x4* c4  = reinterpret_cast<f32x4*>(out + BT + cbase + seg);
    float lps[CSEG];
#pragma unroll
    for (int e = 0; e < 4; ++e) { lps[e] = lq0[e]; lps[4 + e] = lq1[e]; }

    float c = K;
#pragma unroll
    for (int q = CSEG / 4 - 1; q >= 0; --q) {
        f32x4 cq, gq;
#pragma unroll
        for (int e = 3; e >= 0; --e) {
            c = r2[4 * q + e] + GAMMA_F * c;
            cq[e] = c;
            float adv = fminf(fmaxf(wv[4 * q + e] * c, -CLIP_F), CLIP_F);
            gq[e] = adv * lps[4 * q + e];
        }
        __builtin_nontemporal_store(cq, &c4[q]);
        __builtin_nontemporal_store(gq, &go4[q]);
    }
}

extern "C" void kernel_launch(void* const* d_in, const int* in_sizes, int n_in,
                              void* d_out, int out_size, void* d_ws, size_t ws_size,
                              hipStream_t stream) {
    const float* log_probs = (const float*)d_in[0];
    const float* logits    = (const float*)d_in[1];
    const float* weight    = (const float*)d_in[2];
    // d_in[3] = baselines: unused by the reference computation.
    long BT = (long)in_sizes[0];
    int B = (int)(BT / T_LEN);
    int nblocks = B * (T_LEN / CHUNK);
    reinforce_kernel<<<nblocks, NT, 0, stream>>>(log_probs, logits, weight, (float*)d_out, BT);
}

// Round 5
// 31.575 us; speedup vs baseline: 1.5889x; 1.5889x over previous
//
#include <hip/hip_runtime.h>

// REINFORCE fused kernel, chunked with truncated-horizon halo.
// B=1024 rows, T=8192. Each row split into 4 chunks of 2048; each block (256 thr)
// owns one chunk; incoming carry from a 1024-elem halo (gamma^1024=3.35e-5).
// Round-5: REVERT non-temporal stores (L3 write-back absorbs the 64MiB output;
// nt forced it to HBM every replay -> 45% regression). Keep XCD swizzle +
// single barrier.

#define T_LEN 8192
#define CHUNK 2048
#define NT 256
#define CSEG 8
#define GAMMA_F 0.99f
#define CLIP_F 5.0f
#define EPS_F 1e-7f

typedef float f32x4 __attribute__((ext_vector_type(4)));

constexpr double dgpow(int n) {
    double r = 1.0;
    for (int i = 0; i < n; ++i) r *= 0.99;
    return r;
}

__device__ __forceinline__ float r2f(float w, float x) {
    float s = 1.0f / (1.0f + __expf(-x));
    return w * w * __logf(s + EPS_F);
}

__global__ __launch_bounds__(NT)
void reinforce_kernel(const float* __restrict__ log_probs,
                      const float* __restrict__ logits,
                      const float* __restrict__ weight,
                      float* __restrict__ out,   // [2*B*T]: objective, then cumulative
                      long BT) {
    // XCD-aware decode: all 4 chunks of a row share bid%8 -> same XCD L2.
    const int bid  = blockIdx.x;          // 0..4095
    const int k    = bid & 7;             // xcd slot
    const int j    = bid >> 3;            // 0..511
    const int chunk = j & 3;              // 0..3
    const int row   = (j >> 2) * 8 + k;   // 0..1023

    const long rbase = (long)row * T_LEN;
    const long cbase = rbase + (long)chunk * CHUNK;
    const int tid  = threadIdx.x;
    const int lane = tid & 63;
    const int wave = tid >> 6;
    const int seg  = tid * CSEG;

    __shared__ float RED[4];
    __shared__ float WT[4];

    // ---- issue ALL global loads up front ----
    f32x4 hw, hx;
    if (chunk != 3) {
        const long hbase = cbase + CHUNK + (long)tid * 4;
        hw = *reinterpret_cast<const f32x4*>(weight + hbase);
        hx = *reinterpret_cast<const f32x4*>(logits + hbase);
    }
    const f32x4* w4  = reinterpret_cast<const f32x4*>(weight + cbase + seg);
    const f32x4* x4  = reinterpret_cast<const f32x4*>(logits + cbase + seg);
    const f32x4* lp4 = reinterpret_cast<const f32x4*>(log_probs + cbase + seg);
    f32x4 wq0 = w4[0], wq1 = w4[1];
    f32x4 xq0 = x4[0], xq1 = x4[1];
    f32x4 lq0 = lp4[0], lq1 = lp4[1];

    // ---- chunk r2 ----
    float r2[CSEG], wv[CSEG];
#pragma unroll
    for (int e = 0; e < 4; ++e) { wv[e] = wq0[e]; wv[4 + e] = wq1[e]; }
#pragma unroll
    for (int e = 0; e < 4; ++e) { r2[e] = r2f(wq0[e], xq0[e]); r2[4 + e] = r2f(wq1[e], xq1[e]); }

    // ---- per-thread suffix sum (zero carry) ----
    float S = 0.0f;
#pragma unroll
    for (int jj = CSEG - 1; jj >= 0; --jj) S = r2[jj] + GAMMA_F * S;

    // ---- wave suffix scan (decay gamma^8 per lane step) ----
    float X = S;
    {
        constexpr float G8   = (float)dgpow(8);
        constexpr float G16  = (float)dgpow(16);
        constexpr float G32  = (float)dgpow(32);
        constexpr float G64  = (float)dgpow(64);
        constexpr float G128 = (float)dgpow(128);
        constexpr float G256 = (float)dgpow(256);
        float t;
        t = __shfl_down(X, 1, 64);  if (lane + 1  < 64) X += G8   * t;
        t = __shfl_down(X, 2, 64);  if (lane + 2  < 64) X += G16  * t;
        t = __shfl_down(X, 4, 64);  if (lane + 4  < 64) X += G32  * t;
        t = __shfl_down(X, 8, 64);  if (lane + 8  < 64) X += G64  * t;
        t = __shfl_down(X, 16, 64); if (lane + 16 < 64) X += G128 * t;
        t = __shfl_down(X, 32, 64); if (lane + 32 < 64) X += G256 * t;
    }
    float Ex = __shfl_down(X, 1, 64);
    if (lane == 63) Ex = 0.0f;

    // ---- halo partial (independent of scan) ----
    if (chunk != 3) {
        float h0 = r2f(hw[0], hx[0]), h1 = r2f(hw[1], hx[1]);
        float h2 = r2f(hw[2], hx[2]), h3 = r2f(hw[3], hx[3]);
        float hS = h0 + GAMMA_F * (h1 + GAMMA_F * (h2 + GAMMA_F * h3));
        const float L2G4 = 4.0f * -0.014499569695f;   // 4*log2(0.99)
        float part = exp2f((float)tid * L2G4) * hS;
#pragma unroll
        for (int off = 1; off < 64; off <<= 1)
            part += __shfl_xor(part, off, 64);
        if (lane == 0) RED[wave] = part;
    }
    if (lane == 0) WT[wave] = X;

    __syncthreads();   // single barrier

    float c_in = (chunk != 3) ? (RED[0] + RED[1] + RED[2] + RED[3]) : 0.0f;

    constexpr float G512  = (float)dgpow(512);
    constexpr float G1024 = (float)dgpow(1024);
    constexpr float G1536 = (float)dgpow(1536);
    float WC;
    if (wave == 3)      WC = c_in;
    else if (wave == 2) WC = WT[3] + G512 * c_in;
    else if (wave == 1) WC = WT[2] + G512 * WT[3] + G1024 * c_in;
    else                WC = WT[1] + G512 * WT[2] + G1024 * WT[3] + G1536 * c_in;

    const float L2G8 = 8.0f * -0.014499569695f;   // 8*log2(0.99)
    float K = Ex + exp2f((float)(63 - lane) * L2G8) * WC;

    // ---- fixup scan + fused epilogue + write-back stores ----
    f32x4* go4 = reinterpret_cast<f32x4*>(out + cbase + seg);
    f32x4* c4  = reinterpret_cast<f32x4*>(out + BT + cbase + seg);
    float lps[CSEG];
#pragma unroll
    for (int e = 0; e < 4; ++e) { lps[e] = lq0[e]; lps[4 + e] = lq1[e]; }

    float c = K;
#pragma unroll
    for (int q = CSEG / 4 - 1; q >= 0; --q) {
        f32x4 cq, gq;
#pragma unroll
        for (int e = 3; e >= 0; --e) {
            c = r2[4 * q + e] + GAMMA_F * c;
            cq[e] = c;
            float adv = fminf(fmaxf(wv[4 * q + e] * c, -CLIP_F), CLIP_F);
            gq[e] = adv * lps[4 * q + e];
        }
        c4[q]  = cq;
        go4[q] = gq;
    }
}

extern "C" void kernel_launch(void* const* d_in, const int* in_sizes, int n_in,
                              void* d_out, int out_size, void* d_ws, size_t ws_size,
                              hipStream_t stream) {
    const float* log_probs = (const float*)d_in[0];
    const float* logits    = (const float*)d_in[1];
    const float* weight    = (const float*)d_in[2];
    // d_in[3] = baselines: unused by the reference computation.
    long BT = (long)in_sizes[0];
    int B = (int)(BT / T_LEN);
    int nblocks = B * (T_LEN / CHUNK);
    reinforce_kernel<<<nblocks, NT, 0, stream>>>(log_probs, logits, weight, (float*)d_out, BT);
}